// Round 2
// baseline (1591.599 us; speedup 1.0000x reference)
//
#include <hip/hip_runtime.h>
#include <stdint.h>
#include <stddef.h>

// Problem constants
#define BSZ 64
#define MM  2048
#define DD  1024
#define HH  1024
#define RR  (BSZ * MM)   // 131072 rows of the big GEMM

// GEMM tile config: block 256 rows(M) x 128 cols(N), BK=32, 4 waves in 2x2,
// wave tile 128(M) x 64(N) = 8x4 frags of 16x16x32 bf16 MFMA.
#define BM 256
#define BN 128
#define BK 32

typedef float  float4v  __attribute__((ext_vector_type(4)));
typedef short  short4v  __attribute__((ext_vector_type(4)));
typedef short  short8v  __attribute__((ext_vector_type(8)));
typedef __bf16 bf16x4v  __attribute__((ext_vector_type(4)));

// tanh(x) = sign(x) * (1 - 2e/(1+e)), e = exp(-2|x|). No overflow, ~6 VALU ops.
__device__ __forceinline__ float fast_tanh(float x) {
    float ax = __builtin_fabsf(x);
    float e  = __builtin_amdgcn_exp2f(ax * -2.88539008177792681f); // e^{-2ax}
    float r  = __builtin_amdgcn_rcpf(1.0f + e);
    float t  = __builtin_fmaf(-2.0f * e, r, 1.0f);
    return __builtin_copysignf(t, x);
}

// ---------------------------------------------------------------- cast Wm -> bf16
__global__ __launch_bounds__(256) void cast_wm_kernel(const float* __restrict__ wm,
                                                      short* __restrict__ out) {
    int i = (blockIdx.x * 256 + threadIdx.x) * 4;
    float4v f = *(const float4v*)(wm + i);
    union { bf16x4v b; short4v s; } u;
    u.b = __builtin_convertvector(f, bf16x4v);
    *(short4v*)(out + i) = u.s;
}

// ---------------------------------------------------------------- qproj (fp32 exact)
// qproj[b,h] = sum_d query[b,d]*Wq[h,d] + bq[h]
// 4 threads per h (interleaved 16-B chunks), 64 h per block -> 1024 blocks.
__global__ __launch_bounds__(256) void qproj_kernel(const float* __restrict__ query,
                                                    const float* __restrict__ Wq,
                                                    const float* __restrict__ bq,
                                                    float* __restrict__ qproj) {
    __shared__ __align__(16) float qs[DD];
    const int b   = blockIdx.y;
    const int tid = threadIdx.x;
    const int q   = tid & 3;
    const int h   = blockIdx.x * 64 + (tid >> 2);
    for (int i = tid; i < DD; i += 256) qs[i] = query[b * DD + i];
    __syncthreads();
    const float* wrow = Wq + (size_t)h * DD + q * 4;
    float acc = 0.0f;
#pragma unroll 8
    for (int i = 0; i < 64; ++i) {
        float4v w  = *(const float4v*)(wrow + i * 16);
        float4v qq = *(const float4v*)(qs + i * 16 + q * 4);
        acc += w[0] * qq[0] + w[1] * qq[1] + w[2] * qq[2] + w[3] * qq[3];
    }
    acc += __shfl_xor(acc, 1);
    acc += __shfl_xor(acc, 2);
    if (q == 0) qproj[b * HH + h] = acc + bq[h];
}

// ---------------------------------------------------------------- big fused GEMM
// attn[r] += sum_h tanh( (memory @ Wm^T)[r,h] + qproj[b,h] ) * v[h]
// A staged fp32 global -> VGPR -> bf16 cvt -> swizzled LDS (ds_write_b64).
// B staged bf16 via global_load_lds width=16 into swizzled LDS.
// XOR swizzle: row r (64 B = 4 x 16-B granules), k-granule g stored at
// position g ^ ((r>>1)&3)  => frag reads and stage writes both hit all 8
// bank-groups evenly (structural-minimum LDS phases).
__global__ __launch_bounds__(256, 2) void gemm_attn_kernel(
    const float* __restrict__ memf, const short* __restrict__ wmbf,
    const float* __restrict__ qproj, const float* __restrict__ vvec,
    float* __restrict__ attn) {
    __shared__ __align__(16) short As[BM * BK];   // 16 KB bf16, swizzled
    __shared__ __align__(16) short Bs[BN * BK];   // 8 KB bf16, swizzled

    const int tid  = threadIdx.x;
    const int lane = tid & 63;
    const int wave = tid >> 6;
    const int wx = wave & 1, wy = wave >> 1;

    // XCD-aware swizzle: the 8 column-tiles of one row-tile land on one XCD
    // (blockIdx%8 -> XCD); the 1 MB A row-tile stays hot in that XCD's L2.
    const int bi    = blockIdx.x;
    const int xcd   = bi & 7;
    const int idx   = bi >> 3;
    const int tileR = xcd * 64 + (idx >> 3);   // 0..511
    const int tileC = idx & 7;                 // 0..7
    const int r0 = tileR * BM;
    const int h0 = tileC * BN;

    // ---- A staging: thread covers rows m = 32*i + (tid>>3), i=0..7,
    //      4 fp32 at col (tid&7)*4. Per-instr: 8 rows x 128 B contiguous.
    const int arow = tid >> 3;
    const int acol = (tid & 7) * 4;
    const float* aglob = memf + (size_t)(r0 + arow) * DD + acol;
    // LDS write offset: granule jj=(tid>>1)&3 at pos jj ^ ((m>>1)&3), and
    // (m>>1)&3 == (tid>>4)&3 here; half-granule select = tid&1.
    const int apos = ((tid >> 1) & 3) ^ ((tid >> 4) & 3);
    char* awr = (char*)As + (tid >> 3) * 64 + apos * 16 + (tid & 1) * 8;

    // ---- B staging: wave handles chunks 2w,2w+1; chunk j: lane L fills
    //      row n=16j+(L>>2), pos L&3 -> source k-granule (L&3)^((L>>3)&3).
    const short* bsrc[2];
#pragma unroll
    for (int j = 0; j < 2; ++j) {
        int chunk = wave * 2 + j;
        int n  = chunk * 16 + (lane >> 2);
        int gs = (lane & 3) ^ ((lane >> 3) & 3);
        bsrc[j] = wmbf + (size_t)(h0 + n) * DD + gs * 8;
    }

    // ---- fragment read offsets (swizzle folds to lane-constant)
    const int c = lane & 15;
    const int g = lane >> 4;
    const int lane_off = c * 64 + ((g ^ ((c >> 1) & 3)) * 16);
    const char* AsB = (const char*)As + wy * 8192 + lane_off;
    const char* BsB = (const char*)Bs + wx * 4096 + lane_off;

    float4v acc[8][4];
#pragma unroll
    for (int a = 0; a < 8; ++a)
#pragma unroll
        for (int b = 0; b < 4; ++b) acc[a][b] = (float4v)0.0f;

    for (int kt = 0; kt < DD / BK; ++kt) {
        // A global->VGPR loads first: no LDS dependency, overlap prior MFMA.
        float4v av[8];
#pragma unroll
        for (int i = 0; i < 8; ++i)
            av[i] = *(const float4v*)(aglob + (size_t)i * (32 * DD));

        __syncthreads();   // prior iteration done reading LDS
#pragma unroll
        for (int j = 0; j < 2; ++j) {
            __builtin_amdgcn_global_load_lds(
                (const __attribute__((address_space(1))) void*)(bsrc[j]),
                (__attribute__((address_space(3))) void*)((char*)Bs + (wave * 2 + j) * 1024),
                16, 0, 0);
            bsrc[j] += BK;
        }
#pragma unroll
        for (int i = 0; i < 8; ++i) {
            union { bf16x4v b; short4v s; } u;
            u.b = __builtin_convertvector(av[i], bf16x4v);
            *(short4v*)(awr + i * 2048) = u.s;   // ds_write_b64, swizzled
        }
        aglob += BK;
        __syncthreads();   // staging visible

        short8v bfr[4];
#pragma unroll
        for (int nf = 0; nf < 4; ++nf)
            bfr[nf] = *(const short8v*)(BsB + nf * 1024);
#pragma unroll
        for (int mf = 0; mf < 8; ++mf) {
            short8v afr = *(const short8v*)(AsB + mf * 1024);
#pragma unroll
            for (int nf = 0; nf < 4; ++nf)
                acc[mf][nf] = __builtin_amdgcn_mfma_f32_16x16x32_bf16(
                    afr, bfr[nf], acc[mf][nf], 0, 0, 0);
        }
    }

    // Epilogue: tanh(acc + qproj) * v, reduce over h (cols), atomic into attn.
    const int b = tileR >> 3;   // 8 row-tiles of 256 per batch
    float vv[4], qp[4];
#pragma unroll
    for (int nf = 0; nf < 4; ++nf) {
        int h  = h0 + wx * 64 + nf * 16 + c;
        vv[nf] = vvec[h];
        qp[nf] = qproj[b * HH + h];
    }
    // C/D layout: col = lane&15 (h), row = (lane>>4)*4 + reg (memory row).
#pragma unroll
    for (int mf = 0; mf < 8; ++mf) {
        float rs[4] = {0.0f, 0.0f, 0.0f, 0.0f};
#pragma unroll
        for (int nf = 0; nf < 4; ++nf)
#pragma unroll
            for (int r = 0; r < 4; ++r)
                rs[r] += fast_tanh(acc[mf][nf][r] + qp[nf]) * vv[nf];
#pragma unroll
        for (int r = 0; r < 4; ++r) {
            float s = rs[r];
            s += __shfl_xor(s, 1);
            s += __shfl_xor(s, 2);
            s += __shfl_xor(s, 4);
            s += __shfl_xor(s, 8);
            if (c == 0)
                atomicAdd(attn + (r0 + wy * 128 + mf * 16 + g * 4 + r), s);
        }
    }
}

// ---------------------------------------------------------------- softmax over M
__global__ __launch_bounds__(256) void softmax_kernel(const float* __restrict__ attn,
                                                      float* __restrict__ wout) {
    const int b = blockIdx.x, tid = threadIdx.x;
    __shared__ float red[8];
    float a[8];
    float mx = -1e30f;
#pragma unroll
    for (int i = 0; i < 8; ++i) {
        a[i] = attn[b * MM + i * 256 + tid];
        mx = fmaxf(mx, a[i]);
    }
#pragma unroll
    for (int off = 1; off < 64; off <<= 1) mx = fmaxf(mx, __shfl_xor(mx, off));
    if ((tid & 63) == 0) red[tid >> 6] = mx;
    __syncthreads();
    mx = fmaxf(fmaxf(red[0], red[1]), fmaxf(red[2], red[3]));
    float s = 0.0f;
#pragma unroll
    for (int i = 0; i < 8; ++i) {
        a[i] = __builtin_amdgcn_exp2f((a[i] - mx) * 1.4426950408889634f);
        s += a[i];
    }
#pragma unroll
    for (int off = 1; off < 64; off <<= 1) s += __shfl_xor(s, off);
    if ((tid & 63) == 0) red[4 + (tid >> 6)] = s;
    __syncthreads();
    s = red[4] + red[5] + red[6] + red[7];
    float inv = 1.0f / s;
#pragma unroll
    for (int i = 0; i < 8; ++i) wout[b * MM + i * 256 + tid] = a[i] * inv;
}

// ---------------------------------------------------------------- weighted memory
// out2[b,d] = sum_m w[b,m] * memory[b,m,d]; float4 per thread, m split x16.
__global__ __launch_bounds__(256) void wmem_kernel(const float* __restrict__ mem,
                                                   const float* __restrict__ w,
                                                   float* __restrict__ out2) {
    const int b   = blockIdx.y;
    const int m0  = blockIdx.x * 128;
    const int tid = threadIdx.x;
    __shared__ float wsh[128];
    if (tid < 128) wsh[tid] = w[b * MM + m0 + tid];
    __syncthreads();
    const float* mp = mem + ((size_t)(b * MM + m0)) * DD + tid * 4;
    float4v acc = (float4v)0.0f;
#pragma unroll 8
    for (int m = 0; m < 128; ++m) {
        float4v f = *(const float4v*)(mp + (size_t)m * DD);
        acc += f * wsh[m];
    }
    float* o = out2 + b * DD + tid * 4;
    atomicAdd(o + 0, acc[0]);
    atomicAdd(o + 1, acc[1]);
    atomicAdd(o + 2, acc[2]);
    atomicAdd(o + 3, acc[3]);
}

// ---------------------------------------------------------------- launcher
extern "C" void kernel_launch(void* const* d_in, const int* in_sizes, int n_in,
                              void* d_out, int out_size, void* d_ws, size_t ws_size,
                              hipStream_t stream) {
    const float* query  = (const float*)d_in[0];
    const float* memory = (const float*)d_in[1];
    const float* Wq     = (const float*)d_in[2];
    const float* bq     = (const float*)d_in[3];
    const float* Wm     = (const float*)d_in[4];
    const float* v      = (const float*)d_in[5];

    float* out      = (float*)d_out;
    float* wout     = out;                       // weights [64,1,2048]
    float* wmem_out = out + BSZ * MM;            // weighted_memory [64,1,1024]

    char*  ws    = (char*)d_ws;
    float* qproj = (float*)ws;                   // 256 KB
    float* attn  = (float*)(ws + 262144);        // 512 KB
    short* wmbf  = (short*)(ws + 786432);        // 2 MB  (total 2.75 MB of ws)

    hipMemsetAsync(attn, 0, (size_t)RR * sizeof(float), stream);
    hipMemsetAsync(d_out, 0, (size_t)out_size * sizeof(float), stream);

    cast_wm_kernel<<<HH * DD / (256 * 4), 256, 0, stream>>>(Wm, wmbf);
    qproj_kernel<<<dim3(HH / 64, BSZ), 256, 0, stream>>>(query, Wq, bq, qproj);
    gemm_attn_kernel<<<(RR / BM) * (HH / BN), 256, 0, stream>>>(memory, wmbf, qproj, v, attn);
    softmax_kernel<<<BSZ, 256, 0, stream>>>(attn, wout);
    wmem_kernel<<<dim3(MM / 128, BSZ), 256, 0, stream>>>(memory, wout, wmem_out);
}